// Round 3
// baseline (437.835 us; speedup 1.0000x reference)
//
#include <hip/hip_runtime.h>
#include <hip/hip_bf16.h>

#define BB 8
#define NN 128
#define DD 128

// ws float layout: x[131072] hi[131072] hjb[131072]
#define WS_X     0
#define WS_HI    131072
#define WS_HJB   262144

// ---------------- K0: x = embed[tok] ----------------
__global__ void k_embed(const int* __restrict__ tok, const float* __restrict__ embf,
                        float* __restrict__ x) {
    int r = blockIdx.x;        // 0..1023  (b*128+n)
    int t = threadIdx.x;       // 0..127
    int tk = tok[r];
    x[r * DD + t] = embf[tk * DD + t];
}

// ---------------- K1: hi = x@W1a^T ; hjb = x@W1b^T + b1 ----------------
__global__ __launch_bounds__(256) void k_proj(const float* __restrict__ x,
                                              const float* __restrict__ W1f,
                                              const float* __restrict__ b1f,
                                              float* __restrict__ hi, float* __restrict__ hjb) {
    __shared__ float xs[DD];
    int r = blockIdx.x;
    int t = threadIdx.x;
    if (t < DD) xs[t] = x[r * DD + t];
    __syncthreads();
    int e = t & 127;
    int half = t >> 7;                       // 0 -> hi, 1 -> hjb
    const float4* wrow = reinterpret_cast<const float4*>(W1f + e * 256 + half * 128);
    float acc = 0.f;
#pragma unroll
    for (int d4 = 0; d4 < 32; ++d4) {
        float4 w = wrow[d4];
        acc += xs[d4 * 4 + 0] * w.x;
        acc += xs[d4 * 4 + 1] * w.y;
        acc += xs[d4 * 4 + 2] * w.z;
        acc += xs[d4 * 4 + 3] * w.w;
    }
    if (half == 0) hi[r * DD + e] = acc;
    else           hjb[r * DD + e] = acc + b1f[e];
}

// ---------------- K2: per (b,i): M = relu(H@W2^T + b2); x += A_t[b,i,:] @ M ----------------
// H[j][d] = relu(hi[b,i,d] + hjb[b,j,d]); 8x8 register tile per thread, k-tiled by 32.
__global__ __launch_bounds__(256, 2) void k_msg(const float* __restrict__ hi,
                                                const float* __restrict__ hjb,
                                                const float* __restrict__ W2f,
                                                const float* __restrict__ b2f,
                                                const float* __restrict__ Af,
                                                float* __restrict__ x) {
    // stride 132 (=128+4): rows stay 16B-aligned for float4 LDS reads
    __shared__ __align__(16) float HT[32][132];   // HT[d][j]
    __shared__ __align__(16) float WT[32][132];   // WT[d][e] = W2[e][d]
    __shared__ float hi_s[DD];
    __shared__ float a_s[NN];
    __shared__ float b2s[DD];

    int blk = blockIdx.x;
    int b = blk >> 7;
    int i = blk & 127;
    int t = threadIdx.x;

    if (t < 128) {
        hi_s[t] = hi[blk * DD + t];
        a_s[t]  = Af[(b * NN + t) * NN + i];   // A[b, j=t, i]  (A_t[b,i,j])
        b2s[t]  = b2f[t];
    }
    __syncthreads();

    float acc[8][8];
#pragma unroll
    for (int jj = 0; jj < 8; ++jj)
#pragma unroll
        for (int ee = 0; ee < 8; ++ee) acc[jj][ee] = 0.f;

    const float* hjb_b = hjb + b * NN * DD;
    int dd = t & 31;
    int g  = t >> 5;      // 8 staging groups
    int ty = t >> 4;      // j-tile index (16)
    int tx = t & 15;      // e-tile index (16)

    for (int d0 = 0; d0 < DD; d0 += 32) {
#pragma unroll
        for (int p = 0; p < 16; ++p) {
            int j = p * 8 + g;
            HT[dd][j] = fmaxf(hi_s[d0 + dd] + hjb_b[j * DD + d0 + dd], 0.f);
            WT[dd][j] = W2f[j * DD + d0 + dd];  // j plays role of e here
        }
        __syncthreads();
#pragma unroll 2
        for (int d = 0; d < 32; ++d) {
            const float4* hrow = reinterpret_cast<const float4*>(&HT[d][ty * 8]);
            const float4* wrow = reinterpret_cast<const float4*>(&WT[d][tx * 8]);
            float4 h0 = hrow[0], h1 = hrow[1];
            float4 w0 = wrow[0], w1 = wrow[1];
            float hr[8] = {h0.x, h0.y, h0.z, h0.w, h1.x, h1.y, h1.z, h1.w};
            float wr[8] = {w0.x, w0.y, w0.z, w0.w, w1.x, w1.y, w1.z, w1.w};
#pragma unroll
            for (int jj = 0; jj < 8; ++jj)
#pragma unroll
                for (int ee = 0; ee < 8; ++ee)
                    acc[jj][ee] = fmaf(hr[jj], wr[ee], acc[jj][ee]);
        }
        __syncthreads();
    }

    // epilogue: relu(m + b2), weight by a_j, reduce over j
    float (*red)[129] = reinterpret_cast<float(*)[129]>(&HT[0][0]);  // reuse HT storage
#pragma unroll
    for (int ee = 0; ee < 8; ++ee) {
        int e = tx * 8 + ee;
        float s = 0.f;
#pragma unroll
        for (int jj = 0; jj < 8; ++jj)
            s += a_s[ty * 8 + jj] * fmaxf(acc[jj][ee] + b2s[e], 0.f);
        red[ty][e] = s;
    }
    __syncthreads();
    if (t < 128) {
        float m = 0.f;
#pragma unroll
        for (int q = 0; q < 16; ++q) m += red[q][t];
        x[blk * DD + t] += m;
    }
}

// ---------------- K3: head for all 1024 rows; out = x_all[:,0,:] ----------------
__global__ __launch_bounds__(128) void k_head(const float* __restrict__ x,
                                              const float* __restrict__ Wo1f,
                                              const float* __restrict__ bo1f,
                                              const float* __restrict__ Wo2f,
                                              float* __restrict__ out) {
    __shared__ float zs[DD];
    __shared__ float rs[DD];
    int r = blockIdx.x;
    int t = threadIdx.x;
    zs[t] = x[r * DD + t];
    __syncthreads();
    const float4* wrow = reinterpret_cast<const float4*>(Wo1f + t * DD);
    float acc = 0.f;
#pragma unroll
    for (int d4 = 0; d4 < 32; ++d4) {
        float4 w = wrow[d4];
        acc += zs[d4 * 4 + 0] * w.x + zs[d4 * 4 + 1] * w.y
             + zs[d4 * 4 + 2] * w.z + zs[d4 * 4 + 3] * w.w;
    }
    rs[t] = fmaxf(acc + bo1f[t], 0.f);
    __syncthreads();
    if (t < 10) {
        const float* w2r = Wo2f + t * DD;
        float s = 0.f;
#pragma unroll
        for (int e2 = 0; e2 < DD; ++e2) s += rs[e2] * w2r[e2];
        int bb = r >> 7, nn = r & 127;
        out[80 + r * 10 + t] = s;            // x_all (8,128,10) flattened after out (8,10)
        if (nn == 0) out[bb * 10 + t] = s;   // out == x_all[:,0,:]
    }
}

extern "C" void kernel_launch(void* const* d_in, const int* in_sizes, int n_in,
                              void* d_out, int out_size, void* d_ws, size_t ws_size,
                              hipStream_t stream) {
    const int*   tok  = (const int*)d_in[0];
    const float* Af   = (const float*)d_in[1];
    const float* embf = (const float*)d_in[2];
    const float* W1f  = (const float*)d_in[3];
    const float* b1f  = (const float*)d_in[4];
    const float* W2f  = (const float*)d_in[5];
    const float* b2f  = (const float*)d_in[6];
    const float* Wo1f = (const float*)d_in[7];
    const float* bo1f = (const float*)d_in[8];
    const float* Wo2f = (const float*)d_in[9];

    float* ws  = (float*)d_ws;
    float* x   = ws + WS_X;
    float* hi  = ws + WS_HI;
    float* hjb = ws + WS_HJB;
    float* out = (float*)d_out;

    k_embed<<<BB * NN, DD, 0, stream>>>(tok, embf, x);
    for (int rnd = 0; rnd < 5; ++rnd) {
        k_proj<<<BB * NN, 256, 0, stream>>>(x, W1f, b1f, hi, hjb);
        k_msg<<<BB * NN, 256, 0, stream>>>(hi, hjb, W2f, b2f, Af, x);
    }
    k_head<<<BB * NN, 128, 0, stream>>>(x, Wo1f, bo1f, Wo2f, out);
}

// Round 4
// 233.454 us; speedup vs baseline: 1.8755x; 1.8755x over previous
//
#include <hip/hip_runtime.h>
#include <hip/hip_bf16.h>

#define BB 8
#define NN 128
#define DD 128

// ws float layout: x[131072] hi[131072] hjb[131072] w2b[8704 floats worth]
#define WS_X     0
#define WS_HI    131072
#define WS_HJB   262144
#define WS_W2B   393216   // bf16 W2, padded stride 136, 17408 ushorts

typedef __attribute__((ext_vector_type(8))) short bf16x8;
typedef __attribute__((ext_vector_type(4))) float floatx4;

__device__ __forceinline__ unsigned short f2bf(float f) {
    // round-to-nearest-even bf16 (finite inputs only)
    unsigned int bits = __float_as_uint(f);
    unsigned int r = bits + 0x7FFFu + ((bits >> 16) & 1u);
    return (unsigned short)(r >> 16);
}

// ---------------- K0: x = embed[tok]; blocks<128 also convert W2 -> bf16 padded ----------------
__global__ void k_embed(const int* __restrict__ tok, const float* __restrict__ embf,
                        const float* __restrict__ W2f,
                        float* __restrict__ x, unsigned short* __restrict__ w2b) {
    int r = blockIdx.x;        // 0..1023
    int t = threadIdx.x;       // 0..127
    x[r * DD + t] = embf[tok[r] * DD + t];
    if (r < 128) w2b[r * 136 + t] = f2bf(W2f[r * DD + t]);  // pad cols 128..135 unused
}

// ---------------- K1: hi = x@W1a^T ; hjb = x@W1b^T + b1 (fp32, keeps x-path precise) --------
__global__ __launch_bounds__(256) void k_proj(const float* __restrict__ x,
                                              const float* __restrict__ W1f,
                                              const float* __restrict__ b1f,
                                              float* __restrict__ hi, float* __restrict__ hjb) {
    __shared__ __align__(16) float xs[DD];
    int r = blockIdx.x;
    int t = threadIdx.x;
    if (t < DD) xs[t] = x[r * DD + t];
    __syncthreads();
    int e = t & 127;
    int half = t >> 7;
    const float4* wrow = reinterpret_cast<const float4*>(W1f + e * 256 + half * 128);
    float acc = 0.f;
#pragma unroll
    for (int d4 = 0; d4 < 32; ++d4) {
        float4 w = wrow[d4];
        acc += xs[d4 * 4 + 0] * w.x;
        acc += xs[d4 * 4 + 1] * w.y;
        acc += xs[d4 * 4 + 2] * w.z;
        acc += xs[d4 * 4 + 3] * w.w;
    }
    if (half == 0) hi[r * DD + e] = acc;
    else           hjb[r * DD + e] = acc + b1f[e];
}

// ---------------- K2 (MFMA): per (b,i): M = relu(H@W2^T + b2); x += A_t[b,i,:] @ M ----------
// H[j][d] = relu(hi[b,i,d] + hjb[b,j,d]) as bf16 in LDS (stride 136 = +8 pad).
// 4 waves: wave w -> quadrant (j in [ (w>>1)*64, +64 ), e in [ (w&1)*64, +64 )).
// mfma_f32_16x16x32_bf16: A[m=lane&15][k=quad*8+i], B[k][n=lane&15], C col=lane&15,row=quad*4+reg.
__global__ __launch_bounds__(256, 2) void k_msg(const float* __restrict__ hi,
                                                const float* __restrict__ hjb,
                                                const unsigned short* __restrict__ w2b,
                                                const float* __restrict__ b2f,
                                                const float* __restrict__ Af,
                                                float* __restrict__ x) {
    __shared__ __align__(16) unsigned short Hb[128 * 136];
    __shared__ __align__(16) unsigned short Wb[128 * 136];
    __shared__ __align__(16) float his[DD];
    __shared__ float a_s[NN];
    __shared__ float b2s[DD];
    __shared__ float red[2][DD];

    int blk = blockIdx.x;
    int b = blk >> 7;
    int i = blk & 127;
    int t = threadIdx.x;

    if (t < 128) {
        his[t] = hi[blk * DD + t];
        a_s[t] = Af[(b * NN + t) * NN + i];   // A[b, j=t, i]
        b2s[t] = b2f[t];
    }
    // stage W2 bf16 image (17408 ushorts = 2176 uint4)
    {
        const uint4* src = reinterpret_cast<const uint4*>(w2b);
        uint4* dst = reinterpret_cast<uint4*>(Wb);
#pragma unroll
        for (int it = 0; it < 9; ++it) {
            int idx = it * 256 + t;
            if (idx < 2176) dst[idx] = src[idx];
        }
    }
    __syncthreads();   // his ready for H staging

    // stage H = relu(hi + hjb_row) -> bf16, coalesced 1KB/wave chunks
    const float* hjb_b = hjb + b * NN * DD;
#pragma unroll
    for (int it = 0; it < 16; ++it) {
        int lin = it * 1024 + t * 4;
        int j = lin >> 7, d = lin & 127;
        float4 hv = *reinterpret_cast<const float4*>(hjb_b + j * DD + d);
        float4 iv = *reinterpret_cast<const float4*>(his + d);
        ushort4 o;
        o.x = f2bf(fmaxf(hv.x + iv.x, 0.f));
        o.y = f2bf(fmaxf(hv.y + iv.y, 0.f));
        o.z = f2bf(fmaxf(hv.z + iv.z, 0.f));
        o.w = f2bf(fmaxf(hv.w + iv.w, 0.f));
        *reinterpret_cast<ushort4*>(&Hb[j * 136 + d]) = o;
    }
    __syncthreads();

    int wave = t >> 6, lane = t & 63;
    int col = lane & 15, quad = lane >> 4;
    int wq_j = wave >> 1, wq_e = wave & 1;
    int jbase = wq_j * 64, ebase = wq_e * 64;

    floatx4 acc[4][4];   // [jt][et]
#pragma unroll
    for (int jt = 0; jt < 4; ++jt)
#pragma unroll
        for (int et = 0; et < 4; ++et) acc[jt][et] = (floatx4){0.f, 0.f, 0.f, 0.f};

#pragma unroll
    for (int ks = 0; ks < 4; ++ks) {
        int k = ks * 32 + quad * 8;
        bf16x8 af[4], bfr[4];
#pragma unroll
        for (int jt = 0; jt < 4; ++jt)
            af[jt] = *reinterpret_cast<const bf16x8*>(&Hb[(jbase + jt * 16 + col) * 136 + k]);
#pragma unroll
        for (int et = 0; et < 4; ++et)
            bfr[et] = *reinterpret_cast<const bf16x8*>(&Wb[(ebase + et * 16 + col) * 136 + k]);
#pragma unroll
        for (int jt = 0; jt < 4; ++jt)
#pragma unroll
            for (int et = 0; et < 4; ++et)
                acc[jt][et] = __builtin_amdgcn_mfma_f32_16x16x32_bf16(af[jt], bfr[et], acc[jt][et], 0, 0, 0);
    }

    // epilogue: msg_e = sum_j a_j * relu(m_je + b2_e); reduce over quads then waves
#pragma unroll
    for (int et = 0; et < 4; ++et) {
        int e = ebase + et * 16 + col;
        float be = b2s[e];
        float s = 0.f;
#pragma unroll
        for (int jt = 0; jt < 4; ++jt) {
            int j0 = jbase + jt * 16 + quad * 4;
#pragma unroll
            for (int r = 0; r < 4; ++r)
                s += a_s[j0 + r] * fmaxf(acc[jt][et][r] + be, 0.f);
        }
        s += __shfl_xor(s, 16, 64);
        s += __shfl_xor(s, 32, 64);
        if (quad == 0) red[wq_j][e] = s;
    }
    __syncthreads();
    if (t < 128) x[blk * DD + t] += red[0][t] + red[1][t];
}

// ---------------- K3: head for all 1024 rows; out = x_all[:,0,:] ----------------
__global__ __launch_bounds__(128) void k_head(const float* __restrict__ x,
                                              const float* __restrict__ Wo1f,
                                              const float* __restrict__ bo1f,
                                              const float* __restrict__ Wo2f,
                                              float* __restrict__ out) {
    __shared__ __align__(16) float zs[DD];
    __shared__ float rs[DD];
    int r = blockIdx.x;
    int t = threadIdx.x;
    zs[t] = x[r * DD + t];
    __syncthreads();
    const float4* wrow = reinterpret_cast<const float4*>(Wo1f + t * DD);
    float acc = 0.f;
#pragma unroll
    for (int d4 = 0; d4 < 32; ++d4) {
        float4 w = wrow[d4];
        acc += zs[d4 * 4 + 0] * w.x + zs[d4 * 4 + 1] * w.y
             + zs[d4 * 4 + 2] * w.z + zs[d4 * 4 + 3] * w.w;
    }
    rs[t] = fmaxf(acc + bo1f[t], 0.f);
    __syncthreads();
    if (t < 10) {
        const float* w2r = Wo2f + t * DD;
        float s = 0.f;
#pragma unroll
        for (int e2 = 0; e2 < DD; ++e2) s += rs[e2] * w2r[e2];
        int bb = r >> 7, nn = r & 127;
        out[80 + r * 10 + t] = s;            // x_all (8,128,10) after out (8,10)
        if (nn == 0) out[bb * 10 + t] = s;   // out == x_all[:,0,:]
    }
}

extern "C" void kernel_launch(void* const* d_in, const int* in_sizes, int n_in,
                              void* d_out, int out_size, void* d_ws, size_t ws_size,
                              hipStream_t stream) {
    const int*   tok  = (const int*)d_in[0];
    const float* Af   = (const float*)d_in[1];
    const float* embf = (const float*)d_in[2];
    const float* W1f  = (const float*)d_in[3];
    const float* b1f  = (const float*)d_in[4];
    const float* W2f  = (const float*)d_in[5];
    const float* b2f  = (const float*)d_in[6];
    const float* Wo1f = (const float*)d_in[7];
    const float* bo1f = (const float*)d_in[8];
    const float* Wo2f = (const float*)d_in[9];

    float* ws  = (float*)d_ws;
    float* x   = ws + WS_X;
    float* hi  = ws + WS_HI;
    float* hjb = ws + WS_HJB;
    unsigned short* w2b = (unsigned short*)(ws + WS_W2B);
    float* out = (float*)d_out;

    k_embed<<<BB * NN, DD, 0, stream>>>(tok, embf, W2f, x, w2b);
    for (int rnd = 0; rnd < 5; ++rnd) {
        k_proj<<<BB * NN, 256, 0, stream>>>(x, W1f, b1f, hi, hjb);
        k_msg<<<BB * NN, 256, 0, stream>>>(hi, hjb, w2b, b2f, Af, x);
    }
    k_head<<<BB * NN, 128, 0, stream>>>(x, Wo1f, bo1f, Wo2f, out);
}